// Round 1
// baseline (486.328 us; speedup 1.0000x reference)
//
#include <hip/hip_runtime.h>
#include <hip/hip_bf16.h>
#include <stdint.h>

#define BB_ 2
#define SS_ 2048
#define DIM_ 512
#define NH_ 8
#define QK_ 128
#define VD_ 128

typedef __attribute__((ext_vector_type(8))) short bf16x8;
typedef __attribute__((ext_vector_type(4))) float f32x4;
typedef __attribute__((ext_vector_type(8))) unsigned short ushort8;
typedef __attribute__((ext_vector_type(4))) unsigned short ushort4v;

__device__ __forceinline__ unsigned short f2bf(float f) {
  union { float f; unsigned int u; } v; v.f = f;
  unsigned int r = v.u + 0x7FFFu + ((v.u >> 16) & 1u);  // RNE
  return (unsigned short)(r >> 16);
}

__device__ __forceinline__ f32x4 mfma16(bf16x8 a, bf16x8 b, f32x4 c) {
  return __builtin_amdgcn_mfma_f32_16x16x32_bf16(a, b, c, 0, 0, 0);
}

// ---------------- convert / transpose kernels ----------------

__global__ void k_convert_x(const float* __restrict__ x, unsigned short* __restrict__ xb, int n4) {
  int i = blockIdx.x * blockDim.x + threadIdx.x;
  if (i < n4) {
    float4 v = reinterpret_cast<const float4*>(x)[i];
    ushort4v o;
    o[0] = f2bf(v.x); o[1] = f2bf(v.y); o[2] = f2bf(v.z); o[3] = f2bf(v.w);
    reinterpret_cast<ushort4v*>(xb)[i] = o;
  }
}

__global__ void k_transpose_wqkv(const float* __restrict__ wq, const float* __restrict__ wk,
                                 const float* __restrict__ wv, unsigned short* __restrict__ wt) {
  int n = blockIdx.x * blockDim.x + threadIdx.x;  // 0..3071
  if (n >= 3072) return;
  const float* src; int col;
  if (n < 1024)      { src = wq; col = n; }
  else if (n < 2048) { src = wk; col = n - 1024; }
  else               { src = wv; col = n - 2048; }
  unsigned short* dst = wt + (size_t)n * DIM_;
  for (int k0 = 0; k0 < DIM_; k0 += 8) {
    ushort8 buf;
#pragma unroll
    for (int j = 0; j < 8; j++) buf[j] = f2bf(src[(size_t)(k0 + j) * 1024 + col]);
    *reinterpret_cast<ushort8*>(dst + k0) = buf;
  }
}

__global__ void k_transpose_wo(const float* __restrict__ wo, unsigned short* __restrict__ wot) {
  int n = blockIdx.x * blockDim.x + threadIdx.x;  // 0..511
  if (n >= DIM_) return;
  unsigned short* dst = wot + (size_t)n * (NH_ * VD_);
  for (int k0 = 0; k0 < NH_ * VD_; k0 += 8) {
    ushort8 buf;
#pragma unroll
    for (int j = 0; j < 8; j++) buf[j] = f2bf(wo[(size_t)(k0 + j) * DIM_ + n]);
    *reinterpret_cast<ushort8*>(dst + k0) = buf;
  }
}

__global__ void k_concat_bias(const float* __restrict__ bq, const float* __restrict__ bk,
                              const float* __restrict__ bv, float* __restrict__ out) {
  int i = blockIdx.x * blockDim.x + threadIdx.x;
  if (i < 1024) out[i] = bq[i];
  else if (i < 2048) out[i] = bk[i - 1024];
  else if (i < 3072) out[i] = bv[i - 2048];
}

// ---------------- GEMM (A row-major [M][K], BT row-major [N][K], both bf16) ----------------
// EPI=0: QKV epilogue (bias + route to q[b][h][s][d], k[b][h][s][d], vt[b][h][d][s])
// EPI=1: plain fp32 out[m][n] = acc + bias[n]

template <int EPI>
__global__ __launch_bounds__(256) void k_gemm_bt(
    const unsigned short* __restrict__ A, const unsigned short* __restrict__ BT,
    const float* __restrict__ bias, int K,
    unsigned short* __restrict__ oq, unsigned short* __restrict__ ok,
    unsigned short* __restrict__ ovt, float* __restrict__ of) {
  __shared__ __align__(16) unsigned short Al[128][48];
  __shared__ __align__(16) unsigned short Bl[128][48];
  const int tid = threadIdx.x;
  const int lane = tid & 63, wave = tid >> 6;
  const int wm = wave >> 1, wn = wave & 1;
  const int lr = lane & 15, lg = lane >> 4;
  const int m0 = blockIdx.y * 128, n0 = blockIdx.x * 128;
  f32x4 acc[4][4] = {};
  const int srow = tid >> 2, skc = (tid & 3) * 8;

  for (int k0 = 0; k0 < K; k0 += 32) {
    __syncthreads();
#pragma unroll
    for (int p = 0; p < 2; p++) {
      int row = srow + (p << 6);
      *reinterpret_cast<ushort8*>(&Al[row][skc]) =
          *reinterpret_cast<const ushort8*>(A + (size_t)(m0 + row) * K + k0 + skc);
      *reinterpret_cast<ushort8*>(&Bl[row][skc]) =
          *reinterpret_cast<const ushort8*>(BT + (size_t)(n0 + row) * K + k0 + skc);
    }
    __syncthreads();
    bf16x8 af[4], bfr[4];
#pragma unroll
    for (int i = 0; i < 4; i++)
      af[i] = *reinterpret_cast<const bf16x8*>(&Al[wm * 64 + i * 16 + lr][lg * 8]);
#pragma unroll
    for (int i = 0; i < 4; i++)
      bfr[i] = *reinterpret_cast<const bf16x8*>(&Bl[wn * 64 + i * 16 + lr][lg * 8]);
#pragma unroll
    for (int i = 0; i < 4; i++)
#pragma unroll
      for (int j = 0; j < 4; j++)
        acc[i][j] = mfma16(af[i], bfr[j], acc[i][j]);
  }

#pragma unroll
  for (int i = 0; i < 4; i++) {
#pragma unroll
    for (int j = 0; j < 4; j++) {
      const int n = n0 + wn * 64 + j * 16 + lr;
      const float bv = bias[n];
      const int mb = m0 + wm * 64 + i * 16 + lg * 4;
      if (EPI == 0) {
        const int region = n >> 10;
        const int h = (n & 1023) >> 7, d = n & 127;
        if (region == 2) {
          ushort4v pk;
#pragma unroll
          for (int r = 0; r < 4; r++) pk[r] = f2bf(acc[i][j][r] + bv);
          const int bb = mb >> 11, s = mb & 2047;
          *reinterpret_cast<ushort4v*>(ovt + ((size_t)((bb * NH_ + h) * VD_ + d)) * SS_ + s) = pk;
        } else {
          unsigned short* dst = (region == 0) ? oq : ok;
#pragma unroll
          for (int r = 0; r < 4; r++) {
            const int m = mb + r;
            const int bb = m >> 11, s = m & 2047;
            dst[((size_t)((bb * NH_ + h) * SS_ + s)) * QK_ + d] = f2bf(acc[i][j][r] + bv);
          }
        }
      } else {
#pragma unroll
        for (int r = 0; r < 4; r++) {
          const int m = mb + r;
          of[(size_t)m * DIM_ + n] = acc[i][j][r] + bv;
        }
      }
    }
  }
}

// ---------------- flash attention with positional bias ----------------
// grid: (S/64, NH, B); block: 256 = 4 waves, each wave owns 16 q-rows.
// q,k: [b][h][s][128] bf16 ; vt: [b][h][d][s] bf16 ; pe: [h][S][S] fp32
// out att: [b][s][h*128+d] bf16

__global__ __launch_bounds__(256) void k_attn(
    const unsigned short* __restrict__ q, const unsigned short* __restrict__ k,
    const unsigned short* __restrict__ vt, const float* __restrict__ pe,
    unsigned short* __restrict__ att) {
  __shared__ __align__(16) unsigned short P[4][16][72];
  const int qt = blockIdx.x, h = blockIdx.y, b = blockIdx.z;
  const int lane = threadIdx.x & 63, wave = threadIdx.x >> 6;
  const int lr = lane & 15, lg = lane >> 4;
  const int qrow0 = qt * 64 + wave * 16;
  const unsigned short* qp = q + (size_t)(b * NH_ + h) * SS_ * QK_;
  const unsigned short* kp = k + (size_t)(b * NH_ + h) * SS_ * QK_;
  const unsigned short* vp = vt + (size_t)(b * NH_ + h) * VD_ * SS_;
  const float* pep = pe + (size_t)h * SS_ * SS_;

  bf16x8 qf[4];
#pragma unroll
  for (int c = 0; c < 4; c++)
    qf[c] = *reinterpret_cast<const bf16x8*>(qp + (size_t)(qrow0 + lr) * QK_ + c * 32 + lg * 8);

  f32x4 o[8] = {};
  float mrow[4] = {-1e30f, -1e30f, -1e30f, -1e30f};
  float lrow[4] = {0.f, 0.f, 0.f, 0.f};
  const float scale = 0.08838834764831845f;  // 1/sqrt(128)

  for (int kt = 0; kt <= qt; kt++) {
    const int kbase = kt * 64;
    f32x4 sc[4] = {};
#pragma unroll
    for (int cs = 0; cs < 4; cs++) {
#pragma unroll
      for (int c = 0; c < 4; c++) {
        bf16x8 kf = *reinterpret_cast<const bf16x8*>(
            kp + (size_t)(kbase + cs * 16 + lr) * QK_ + c * 32 + lg * 8);
        sc[cs] = mfma16(qf[c], kf, sc[cs]);
      }
    }
    float tmax[4] = {-1e30f, -1e30f, -1e30f, -1e30f};
#pragma unroll
    for (int cs = 0; cs < 4; cs++) {
      const int col = kbase + cs * 16 + lr;
#pragma unroll
      for (int r = 0; r < 4; r++) {
        const int row = qrow0 + lg * 4 + r;
        float v;
        if (col > row) v = -1e30f;  // causal
        else v = sc[cs][r] * scale + pep[(size_t)row * SS_ + col];
        sc[cs][r] = v;
        tmax[r] = fmaxf(tmax[r], v);
      }
    }
#pragma unroll
    for (int r = 0; r < 4; r++) {
      float t = tmax[r];
      t = fmaxf(t, __shfl_xor(t, 1));
      t = fmaxf(t, __shfl_xor(t, 2));
      t = fmaxf(t, __shfl_xor(t, 4));
      t = fmaxf(t, __shfl_xor(t, 8));
      tmax[r] = t;
    }
    float pscale[4];
#pragma unroll
    for (int r = 0; r < 4; r++) {
      const float mnew = fmaxf(mrow[r], tmax[r]);
      pscale[r] = __expf(mrow[r] - mnew);
      mrow[r] = mnew;
      lrow[r] *= pscale[r];
    }
#pragma unroll
    for (int sub = 0; sub < 8; sub++)
#pragma unroll
      for (int r = 0; r < 4; r++) o[sub][r] *= pscale[r];

    float rsum[4] = {0.f, 0.f, 0.f, 0.f};
#pragma unroll
    for (int cs = 0; cs < 4; cs++)
#pragma unroll
      for (int r = 0; r < 4; r++) {
        const float p = __expf(sc[cs][r] - mrow[r]);
        sc[cs][r] = p;
        rsum[r] += p;
      }
#pragma unroll
    for (int r = 0; r < 4; r++) {
      float t = rsum[r];
      t += __shfl_xor(t, 1);
      t += __shfl_xor(t, 2);
      t += __shfl_xor(t, 4);
      t += __shfl_xor(t, 8);
      lrow[r] += t;
    }
#pragma unroll
    for (int cs = 0; cs < 4; cs++)
#pragma unroll
      for (int r = 0; r < 4; r++)
        P[wave][lg * 4 + r][cs * 16 + lr] = f2bf(sc[cs][r]);

#pragma unroll
    for (int kk = 0; kk < 2; kk++) {
      const bf16x8 pf = *reinterpret_cast<const bf16x8*>(&P[wave][lr][kk * 32 + lg * 8]);
#pragma unroll
      for (int sub = 0; sub < 8; sub++) {
        const bf16x8 vf = *reinterpret_cast<const bf16x8*>(
            vp + (size_t)(sub * 16 + lr) * SS_ + kbase + kk * 32 + lg * 8);
        o[sub] = mfma16(pf, vf, o[sub]);
      }
    }
  }

#pragma unroll
  for (int r = 0; r < 4; r++) {
    const float inv = 1.0f / lrow[r];
    const int row = qrow0 + lg * 4 + r;
#pragma unroll
    for (int sub = 0; sub < 8; sub++) {
      att[(size_t)(b * SS_ + row) * (NH_ * VD_) + h * VD_ + sub * 16 + lr] =
          f2bf(o[sub][r] * inv);
    }
  }
}

// ---------------- launcher ----------------

extern "C" void kernel_launch(void* const* d_in, const int* in_sizes, int n_in,
                              void* d_out, int out_size, void* d_ws, size_t ws_size,
                              hipStream_t stream) {
  const float* x    = (const float*)d_in[0];
  const float* pe   = (const float*)d_in[3];
  const float* wq_w = (const float*)d_in[4];
  const float* wq_b = (const float*)d_in[5];
  const float* wk_w = (const float*)d_in[6];
  const float* wk_b = (const float*)d_in[7];
  const float* wv_w = (const float*)d_in[8];
  const float* wv_b = (const float*)d_in[9];
  const float* wo_w = (const float*)d_in[10];
  const float* wo_b = (const float*)d_in[11];
  float* out = (float*)d_out;

  char* ws = (char*)d_ws;
  unsigned short* x_bf   = (unsigned short*)(ws);                 // 4 MB
  unsigned short* wqkv_t = (unsigned short*)(ws + 4194304);       // 3 MB
  unsigned short* wo_t   = (unsigned short*)(ws + 7340032);       // 1 MB
  float*          qkv_b  = (float*)(ws + 8388608);                // 12 KB
  unsigned short* qb     = (unsigned short*)(ws + 8400896);       // 8 MB
  unsigned short* kb     = (unsigned short*)(ws + 16789504);      // 8 MB
  unsigned short* vtb    = (unsigned short*)(ws + 25178112);      // 8 MB
  unsigned short* attb   = (unsigned short*)(ws + 33566720);      // 8 MB (total ~42 MB)

  k_convert_x<<<2048, 256, 0, stream>>>(x, x_bf, (4096 * 512) / 4);
  k_transpose_wqkv<<<12, 256, 0, stream>>>(wq_w, wk_w, wv_w, wqkv_t);
  k_transpose_wo<<<2, 256, 0, stream>>>(wo_w, wo_t);
  k_concat_bias<<<12, 256, 0, stream>>>(wq_b, wk_b, wv_b, qkv_b);

  dim3 g1(24, 32);  // N=3072/128, M=4096/128
  k_gemm_bt<0><<<g1, 256, 0, stream>>>(x_bf, wqkv_t, qkv_b, 512, qb, kb, vtb, nullptr);

  dim3 g2(SS_ / 64, NH_, BB_);
  k_attn<<<g2, 256, 0, stream>>>(qb, kb, vtb, pe, attb);

  dim3 g3(4, 32);   // N=512/128, M=4096/128
  k_gemm_bt<1><<<g3, 256, 0, stream>>>(attb, wo_t, wo_b, 1024, nullptr, nullptr, nullptr, out);
}

// Round 2
// 311.620 us; speedup vs baseline: 1.5606x; 1.5606x over previous
//
#include <hip/hip_runtime.h>
#include <hip/hip_bf16.h>
#include <stdint.h>

#define BB_ 2
#define SS_ 2048
#define DIM_ 512
#define NH_ 8
#define QK_ 128
#define VD_ 128

typedef __attribute__((ext_vector_type(8))) short bf16x8;
typedef __attribute__((ext_vector_type(4))) float f32x4;
typedef __attribute__((ext_vector_type(8))) unsigned short ushort8;
typedef __attribute__((ext_vector_type(4))) unsigned short ushort4v;

__device__ __forceinline__ unsigned short f2bf(float f) {
  union { float f; unsigned int u; } v; v.f = f;
  unsigned int r = v.u + 0x7FFFu + ((v.u >> 16) & 1u);  // RNE
  return (unsigned short)(r >> 16);
}

__device__ __forceinline__ f32x4 mfma16(bf16x8 a, bf16x8 b, f32x4 c) {
  return __builtin_amdgcn_mfma_f32_16x16x32_bf16(a, b, c, 0, 0, 0);
}

// ---------------- convert / transpose kernels ----------------

__global__ void k_convert_x(const float* __restrict__ x, unsigned short* __restrict__ xb, int n4) {
  int i = blockIdx.x * blockDim.x + threadIdx.x;
  if (i < n4) {
    float4 v = reinterpret_cast<const float4*>(x)[i];
    ushort4v o;
    o[0] = f2bf(v.x); o[1] = f2bf(v.y); o[2] = f2bf(v.z); o[3] = f2bf(v.w);
    reinterpret_cast<ushort4v*>(xb)[i] = o;
  }
}

// src [R][C] fp32 -> dst [C][R] bf16 ; grid (C/64, R/64), block 256
__global__ void k_transpose_cvt(const float* __restrict__ src, unsigned short* __restrict__ dst,
                                int R, int C) {
  __shared__ float t[64][65];
  const int c0 = blockIdx.x * 64, r0 = blockIdx.y * 64;
  const int tid = threadIdx.x;
  const int rr = tid >> 4, cc4 = (tid & 15) * 4;
#pragma unroll
  for (int p = 0; p < 4; p++) {
    float4 v = *reinterpret_cast<const float4*>(src + (size_t)(r0 + rr + p * 16) * C + c0 + cc4);
    t[rr + p * 16][cc4 + 0] = v.x; t[rr + p * 16][cc4 + 1] = v.y;
    t[rr + p * 16][cc4 + 2] = v.z; t[rr + p * 16][cc4 + 3] = v.w;
  }
  __syncthreads();
  const int cl = tid >> 2, rb = (tid & 3) * 16;
#pragma unroll
  for (int g = 0; g < 2; g++) {
    ushort8 o;
#pragma unroll
    for (int j = 0; j < 8; j++) o[j] = f2bf(t[rb + g * 8 + j][cl]);
    *reinterpret_cast<ushort8*>(dst + (size_t)(c0 + cl) * R + r0 + rb + g * 8) = o;
  }
}

__global__ void k_concat_bias(const float* __restrict__ bq, const float* __restrict__ bk,
                              const float* __restrict__ bv, float* __restrict__ out) {
  int i = blockIdx.x * blockDim.x + threadIdx.x;
  if (i < 1024) out[i] = bq[i];
  else if (i < 2048) out[i] = bk[i - 1024];
  else if (i < 3072) out[i] = bv[i - 2048];
}

// ---------------- GEMM (A row-major [M][K], BT row-major [N][K], both bf16) ----------------

template <int EPI>
__global__ __launch_bounds__(256) void k_gemm_bt(
    const unsigned short* __restrict__ A, const unsigned short* __restrict__ BT,
    const float* __restrict__ bias, int K,
    unsigned short* __restrict__ oq, unsigned short* __restrict__ ok,
    unsigned short* __restrict__ ovt, float* __restrict__ of) {
  __shared__ __align__(16) unsigned short Al[128][48];
  __shared__ __align__(16) unsigned short Bl[128][48];
  const int tid = threadIdx.x;
  const int lane = tid & 63, wave = tid >> 6;
  const int wm = wave >> 1, wn = wave & 1;
  const int lr = lane & 15, lg = lane >> 4;
  const int m0 = blockIdx.y * 128, n0 = blockIdx.x * 128;
  f32x4 acc[4][4] = {};
  const int srow = tid >> 2, skc = (tid & 3) * 8;

  for (int k0 = 0; k0 < K; k0 += 32) {
    __syncthreads();
#pragma unroll
    for (int p = 0; p < 2; p++) {
      int row = srow + (p << 6);
      *reinterpret_cast<ushort8*>(&Al[row][skc]) =
          *reinterpret_cast<const ushort8*>(A + (size_t)(m0 + row) * K + k0 + skc);
      *reinterpret_cast<ushort8*>(&Bl[row][skc]) =
          *reinterpret_cast<const ushort8*>(BT + (size_t)(n0 + row) * K + k0 + skc);
    }
    __syncthreads();
    bf16x8 af[4], bfr[4];
#pragma unroll
    for (int i = 0; i < 4; i++)
      af[i] = *reinterpret_cast<const bf16x8*>(&Al[wm * 64 + i * 16 + lr][lg * 8]);
#pragma unroll
    for (int i = 0; i < 4; i++)
      bfr[i] = *reinterpret_cast<const bf16x8*>(&Bl[wn * 64 + i * 16 + lr][lg * 8]);
#pragma unroll
    for (int i = 0; i < 4; i++)
#pragma unroll
      for (int j = 0; j < 4; j++)
        acc[i][j] = mfma16(af[i], bfr[j], acc[i][j]);
  }

#pragma unroll
  for (int i = 0; i < 4; i++) {
#pragma unroll
    for (int j = 0; j < 4; j++) {
      const int n = n0 + wn * 64 + j * 16 + lr;
      const float bv = bias[n];
      const int mb = m0 + wm * 64 + i * 16 + lg * 4;
      if (EPI == 0) {
        const int region = n >> 10;
        const int h = (n & 1023) >> 7, d = n & 127;
        if (region == 2) {
          ushort4v pk;
#pragma unroll
          for (int r = 0; r < 4; r++) pk[r] = f2bf(acc[i][j][r] + bv);
          const int bb = mb >> 11, s = mb & 2047;
          *reinterpret_cast<ushort4v*>(ovt + ((size_t)((bb * NH_ + h) * VD_ + d)) * SS_ + s) = pk;
        } else {
          unsigned short* dst = (region == 0) ? oq : ok;
#pragma unroll
          for (int r = 0; r < 4; r++) {
            const int m = mb + r;
            const int bb = m >> 11, s = m & 2047;
            dst[((size_t)((bb * NH_ + h) * SS_ + s)) * QK_ + d] = f2bf(acc[i][j][r] + bv);
          }
        }
      } else {
#pragma unroll
        for (int r = 0; r < 4; r++) {
          const int m = mb + r;
          of[(size_t)m * DIM_ + n] = acc[i][j][r] + bv;
        }
      }
    }
  }
}

// ---------------- flash attention, double-buffered LDS pipeline ----------------
// grid (32, NH, B), block 256 = 4 waves x 16 q-rows. K-tile + pe-tile staged to LDS
// via global_load_lds (linear dest, XOR-swizzled source, swizzled read). V direct global.

__global__ __launch_bounds__(256) void k_attn(
    const unsigned short* __restrict__ q, const unsigned short* __restrict__ k,
    const unsigned short* __restrict__ vt, const float* __restrict__ pe,
    unsigned short* __restrict__ att) {
  __shared__ __align__(16) unsigned short Kl[2][64][128];  // 32 KB
  __shared__ __align__(16) float PEl[2][64][64];           // 32 KB
  __shared__ __align__(16) unsigned short P[4][16][72];    // 9 KB

  const int h = blockIdx.y, b = blockIdx.z;
  const int xi = (blockIdx.x + (blockIdx.z << 4)) & 31;
  const int qt = (xi < 16) ? xi : 47 - xi;  // same-CU (z-striped) pair sums to 33 tiles

  const int lane = threadIdx.x & 63, wave = threadIdx.x >> 6;
  const int lr = lane & 15, lg = lane >> 4;
  const int qrow0b = qt * 64;
  const int qrow0 = qrow0b + wave * 16;

  const unsigned short* qp = q + (size_t)(b * NH_ + h) * SS_ * QK_;
  const unsigned short* kp = k + (size_t)(b * NH_ + h) * SS_ * QK_;
  const unsigned short* vp = vt + (size_t)(b * NH_ + h) * VD_ * SS_;
  const float* pep = pe + (size_t)h * SS_ * SS_;

  // staging: wave handles segments s = wave*4 .. wave*4+3; seg s = rows 4s..4s+3 (256B/row)
  const int st_row_in_seg = lane >> 4;          // 0..3
  const int st_colb = (lane & 15) * 16;         // 0..240
  auto stage = [&](int kt, int buf) {
#pragma unroll
    for (int i = 0; i < 4; i++) {
      const int s = wave * 4 + i;
      const int row = s * 4 + st_row_in_seg;    // block-local row 0..63
      const int sw = (row & 7) << 4;
      const char* gk = (const char*)(kp + (size_t)(kt * 64 + row) * QK_) + (st_colb ^ sw);
      __builtin_amdgcn_global_load_lds((const unsigned int*)gk,
                                       (unsigned int*)&Kl[buf][s * 4][0], 16, 0, 0);
      const char* gp = (const char*)(pep + (size_t)(qrow0b + row) * SS_ + kt * 64) + (st_colb ^ sw);
      __builtin_amdgcn_global_load_lds((const unsigned int*)gp,
                                       (unsigned int*)&PEl[buf][s * 4][0], 16, 0, 0);
    }
  };

  bf16x8 qf[4];
#pragma unroll
  for (int c = 0; c < 4; c++)
    qf[c] = *reinterpret_cast<const bf16x8*>(qp + (size_t)(qrow0 + lr) * QK_ + c * 32 + lg * 8);

  f32x4 o[8] = {};
  float mrow[4] = {-1e30f, -1e30f, -1e30f, -1e30f};
  float lrow[4] = {0.f, 0.f, 0.f, 0.f};
  const float scale = 0.08838834764831845f;  // 1/sqrt(128)

  stage(0, 0);
  __syncthreads();

  for (int kt = 0; kt <= qt; kt++) {
    const int cur = kt & 1;
    if (kt < qt) stage(kt + 1, cur ^ 1);  // prefetch next tile (hides under compute)
    const int kbase = kt * 64;

    // V fragments: issue early, consume after softmax
    bf16x8 vf[2][8];
#pragma unroll
    for (int kk = 0; kk < 2; kk++)
#pragma unroll
      for (int sub = 0; sub < 8; sub++)
        vf[kk][sub] = *reinterpret_cast<const bf16x8*>(
            vp + (size_t)(sub * 16 + lr) * SS_ + kbase + kk * 32 + lg * 8);

    // QK^T from swizzled LDS K tile
    f32x4 sc[4] = {};
    const char* Kb = (const char*)&Kl[cur][0][0];
#pragma unroll
    for (int cs = 0; cs < 4; cs++) {
      const int row = cs * 16 + lr;
      const int sw = (row & 7) << 4;
#pragma unroll
      for (int c = 0; c < 4; c++) {
        bf16x8 kf = *reinterpret_cast<const bf16x8*>(Kb + row * 256 + ((c * 64 + lg * 16) ^ sw));
        sc[cs] = mfma16(qf[c], kf, sc[cs]);
      }
    }

    // scale + pe (from LDS) + causal mask (diagonal tile only) + online softmax
    const float* Pb = &PEl[cur][0][0];
    const bool diag = (kt == qt);
    float tmax[4] = {-1e30f, -1e30f, -1e30f, -1e30f};
#pragma unroll
    for (int cs = 0; cs < 4; cs++) {
      const int cl = cs * 16 + lr;
#pragma unroll
      for (int r = 0; r < 4; r++) {
        const int ql = wave * 16 + lg * 4 + r;  // block-local q-row
        const float peval = Pb[ql * 64 + ((((unsigned)cl * 4) ^ ((ql & 7) << 4)) >> 2)];
        float v = fmaf(sc[cs][r], scale, peval);
        if (diag && cl > ql) v = -1e30f;
        sc[cs][r] = v;
        tmax[r] = fmaxf(tmax[r], v);
      }
    }
#pragma unroll
    for (int r = 0; r < 4; r++) {
      float t = tmax[r];
      t = fmaxf(t, __shfl_xor(t, 1));
      t = fmaxf(t, __shfl_xor(t, 2));
      t = fmaxf(t, __shfl_xor(t, 4));
      t = fmaxf(t, __shfl_xor(t, 8));
      tmax[r] = t;
    }
    float pscale[4];
#pragma unroll
    for (int r = 0; r < 4; r++) {
      const float mnew = fmaxf(mrow[r], tmax[r]);
      pscale[r] = __expf(mrow[r] - mnew);
      mrow[r] = mnew;
      lrow[r] *= pscale[r];
    }
#pragma unroll
    for (int sub = 0; sub < 8; sub++)
#pragma unroll
      for (int r = 0; r < 4; r++) o[sub][r] *= pscale[r];

    float rsum[4] = {0.f, 0.f, 0.f, 0.f};
#pragma unroll
    for (int cs = 0; cs < 4; cs++)
#pragma unroll
      for (int r = 0; r < 4; r++) {
        const float p = __expf(sc[cs][r] - mrow[r]);
        sc[cs][r] = p;
        rsum[r] += p;
      }
#pragma unroll
    for (int r = 0; r < 4; r++) {
      float t = rsum[r];
      t += __shfl_xor(t, 1);
      t += __shfl_xor(t, 2);
      t += __shfl_xor(t, 4);
      t += __shfl_xor(t, 8);
      lrow[r] += t;
    }
#pragma unroll
    for (int cs = 0; cs < 4; cs++)
#pragma unroll
      for (int r = 0; r < 4; r++)
        P[wave][lg * 4 + r][cs * 16 + lr] = f2bf(sc[cs][r]);

#pragma unroll
    for (int kk = 0; kk < 2; kk++) {
      const bf16x8 pf = *reinterpret_cast<const bf16x8*>(&P[wave][lr][kk * 32 + lg * 8]);
#pragma unroll
      for (int sub = 0; sub < 8; sub++)
        o[sub] = mfma16(pf, vf[kk][sub], o[sub]);
    }

    if (kt < qt) __syncthreads();  // staged buffer ready; all reads of other buffer done
  }

#pragma unroll
  for (int r = 0; r < 4; r++) {
    const float inv = 1.0f / lrow[r];
    const int row = qrow0 + lg * 4 + r;
#pragma unroll
    for (int sub = 0; sub < 8; sub++) {
      att[(size_t)(b * SS_ + row) * (NH_ * VD_) + h * VD_ + sub * 16 + lr] =
          f2bf(o[sub][r] * inv);
    }
  }
}

// ---------------- launcher ----------------

extern "C" void kernel_launch(void* const* d_in, const int* in_sizes, int n_in,
                              void* d_out, int out_size, void* d_ws, size_t ws_size,
                              hipStream_t stream) {
  const float* x    = (const float*)d_in[0];
  const float* pe   = (const float*)d_in[3];
  const float* wq_w = (const float*)d_in[4];
  const float* wq_b = (const float*)d_in[5];
  const float* wk_w = (const float*)d_in[6];
  const float* wk_b = (const float*)d_in[7];
  const float* wv_w = (const float*)d_in[8];
  const float* wv_b = (const float*)d_in[9];
  const float* wo_w = (const float*)d_in[10];
  const float* wo_b = (const float*)d_in[11];
  float* out = (float*)d_out;

  char* ws = (char*)d_ws;
  unsigned short* x_bf   = (unsigned short*)(ws);                 // 4 MB
  unsigned short* wqkv_t = (unsigned short*)(ws + 4194304);       // 3 MB
  unsigned short* wo_t   = (unsigned short*)(ws + 7340032);       // 1 MB
  float*          qkv_b  = (float*)(ws + 8388608);                // 12 KB
  unsigned short* qb     = (unsigned short*)(ws + 8400896);       // 8 MB
  unsigned short* kb     = (unsigned short*)(ws + 16789504);      // 8 MB
  unsigned short* vtb    = (unsigned short*)(ws + 25178112);      // 8 MB
  unsigned short* attb   = (unsigned short*)(ws + 33566720);      // 8 MB

  k_convert_x<<<2048, 256, 0, stream>>>(x, x_bf, (4096 * 512) / 4);
  {
    dim3 gt(16, 8);  // C=1024, R=512
    k_transpose_cvt<<<gt, 256, 0, stream>>>(wq_w, wqkv_t, 512, 1024);
    k_transpose_cvt<<<gt, 256, 0, stream>>>(wk_w, wqkv_t + 1024 * 512, 512, 1024);
    k_transpose_cvt<<<gt, 256, 0, stream>>>(wv_w, wqkv_t + 2048 * 512, 512, 1024);
    dim3 gt2(8, 16);  // C=512, R=1024
    k_transpose_cvt<<<gt2, 256, 0, stream>>>(wo_w, wo_t, 1024, 512);
  }
  k_concat_bias<<<12, 256, 0, stream>>>(wq_b, wk_b, wv_b, qkv_b);

  dim3 g1(24, 32);
  k_gemm_bt<0><<<g1, 256, 0, stream>>>(x_bf, wqkv_t, qkv_b, 512, qb, kb, vtb, nullptr);

  dim3 g2(32, NH_, BB_);
  k_attn<<<g2, 256, 0, stream>>>(qb, kb, vtb, pe, attb);

  dim3 g3(4, 32);
  k_gemm_bt<1><<<g3, 256, 0, stream>>>(attb, wo_t, wo_b, 1024, nullptr, nullptr, nullptr, out);
}

// Round 3
// 205.879 us; speedup vs baseline: 2.3622x; 1.5136x over previous
//
#include <hip/hip_runtime.h>
#include <hip/hip_bf16.h>
#include <stdint.h>

#define BB_ 2
#define SS_ 2048
#define DIM_ 512
#define NH_ 8
#define QK_ 128
#define VD_ 128

typedef __attribute__((ext_vector_type(8))) short bf16x8;
typedef __attribute__((ext_vector_type(4))) float f32x4;
typedef __attribute__((ext_vector_type(8))) unsigned short ushort8;
typedef __attribute__((ext_vector_type(4))) unsigned short ushort4v;

__device__ __forceinline__ unsigned short f2bf(float f) {
  union { float f; unsigned int u; } v; v.f = f;
  unsigned int r = v.u + 0x7FFFu + ((v.u >> 16) & 1u);  // RNE
  return (unsigned short)(r >> 16);
}

__device__ __forceinline__ f32x4 mfma16(bf16x8 a, bf16x8 b, f32x4 c) {
  return __builtin_amdgcn_mfma_f32_16x16x32_bf16(a, b, c, 0, 0, 0);
}

// ---------------- convert / transpose kernels ----------------

__global__ void k_convert_x(const float* __restrict__ x, unsigned short* __restrict__ xb, int n4) {
  int i = blockIdx.x * blockDim.x + threadIdx.x;
  if (i < n4) {
    float4 v = reinterpret_cast<const float4*>(x)[i];
    ushort4v o;
    o[0] = f2bf(v.x); o[1] = f2bf(v.y); o[2] = f2bf(v.z); o[3] = f2bf(v.w);
    reinterpret_cast<ushort4v*>(xb)[i] = o;
  }
}

// src [R][C] fp32 -> dst [C][R] bf16 ; grid (C/64, R/64), block 256
__global__ void k_transpose_cvt(const float* __restrict__ src, unsigned short* __restrict__ dst,
                                int R, int C) {
  __shared__ float t[64][65];
  const int c0 = blockIdx.x * 64, r0 = blockIdx.y * 64;
  const int tid = threadIdx.x;
  const int rr = tid >> 4, cc4 = (tid & 15) * 4;
#pragma unroll
  for (int p = 0; p < 4; p++) {
    float4 v = *reinterpret_cast<const float4*>(src + (size_t)(r0 + rr + p * 16) * C + c0 + cc4);
    t[rr + p * 16][cc4 + 0] = v.x; t[rr + p * 16][cc4 + 1] = v.y;
    t[rr + p * 16][cc4 + 2] = v.z; t[rr + p * 16][cc4 + 3] = v.w;
  }
  __syncthreads();
  const int cl = tid >> 2, rb = (tid & 3) * 16;
#pragma unroll
  for (int g = 0; g < 2; g++) {
    ushort8 o;
#pragma unroll
    for (int j = 0; j < 8; j++) o[j] = f2bf(t[rb + g * 8 + j][cl]);
    *reinterpret_cast<ushort8*>(dst + (size_t)(c0 + cl) * R + r0 + rb + g * 8) = o;
  }
}

__global__ void k_concat_bias(const float* __restrict__ bq, const float* __restrict__ bk,
                              const float* __restrict__ bv, float* __restrict__ out) {
  int i = blockIdx.x * blockDim.x + threadIdx.x;
  if (i < 1024) out[i] = bq[i];
  else if (i < 2048) out[i] = bk[i - 1024];
  else if (i < 3072) out[i] = bv[i - 2048];
}

// ---------------- GEMM (A row-major [M][K], BT row-major [N][K], both bf16) ----------------

template <int EPI>
__global__ __launch_bounds__(256) void k_gemm_bt(
    const unsigned short* __restrict__ A, const unsigned short* __restrict__ BT,
    const float* __restrict__ bias, int K,
    unsigned short* __restrict__ oq, unsigned short* __restrict__ ok,
    unsigned short* __restrict__ ovt, float* __restrict__ of) {
  __shared__ __align__(16) unsigned short Al[128][48];
  __shared__ __align__(16) unsigned short Bl[128][48];
  const int tid = threadIdx.x;
  const int lane = tid & 63, wave = tid >> 6;
  const int wm = wave >> 1, wn = wave & 1;
  const int lr = lane & 15, lg = lane >> 4;
  const int m0 = blockIdx.y * 128, n0 = blockIdx.x * 128;
  f32x4 acc[4][4] = {};
  const int srow = tid >> 2, skc = (tid & 3) * 8;

  for (int k0 = 0; k0 < K; k0 += 32) {
    __syncthreads();
#pragma unroll
    for (int p = 0; p < 2; p++) {
      int row = srow + (p << 6);
      *reinterpret_cast<ushort8*>(&Al[row][skc]) =
          *reinterpret_cast<const ushort8*>(A + (size_t)(m0 + row) * K + k0 + skc);
      *reinterpret_cast<ushort8*>(&Bl[row][skc]) =
          *reinterpret_cast<const ushort8*>(BT + (size_t)(n0 + row) * K + k0 + skc);
    }
    __syncthreads();
    bf16x8 af[4], bfr[4];
#pragma unroll
    for (int i = 0; i < 4; i++)
      af[i] = *reinterpret_cast<const bf16x8*>(&Al[wm * 64 + i * 16 + lr][lg * 8]);
#pragma unroll
    for (int i = 0; i < 4; i++)
      bfr[i] = *reinterpret_cast<const bf16x8*>(&Bl[wn * 64 + i * 16 + lr][lg * 8]);
#pragma unroll
    for (int i = 0; i < 4; i++)
#pragma unroll
      for (int j = 0; j < 4; j++)
        acc[i][j] = mfma16(af[i], bfr[j], acc[i][j]);
  }

#pragma unroll
  for (int i = 0; i < 4; i++) {
#pragma unroll
    for (int j = 0; j < 4; j++) {
      const int n = n0 + wn * 64 + j * 16 + lr;
      const float bv = bias[n];
      const int mb = m0 + wm * 64 + i * 16 + lg * 4;
      if (EPI == 0) {
        const int region = n >> 10;
        const int h = (n & 1023) >> 7, d = n & 127;
        if (region == 2) {
          ushort4v pk;
#pragma unroll
          for (int r = 0; r < 4; r++) pk[r] = f2bf(acc[i][j][r] + bv);
          const int bb = mb >> 11, s = mb & 2047;
          *reinterpret_cast<ushort4v*>(ovt + ((size_t)((bb * NH_ + h) * VD_ + d)) * SS_ + s) = pk;
        } else {
          unsigned short* dst = (region == 0) ? oq : ok;
#pragma unroll
          for (int r = 0; r < 4; r++) {
            const int m = mb + r;
            const int bb = m >> 11, s = m & 2047;
            dst[((size_t)((bb * NH_ + h) * SS_ + s)) * QK_ + d] = f2bf(acc[i][j][r] + bv);
          }
        }
      } else {
#pragma unroll
        for (int r = 0; r < 4; r++) {
          const int m = mb + r;
          of[(size_t)m * DIM_ + n] = acc[i][j][r] + bv;
        }
      }
    }
  }
}

// ---------------- flash attention, S^T structure, barrier-free ----------------
// grid (32, NH, B), block 256 = 4 waves x 16 q-rows each.
// Scores computed transposed: mfma(K-frag, Q-frag) -> S^T[k][q], so each lane
// owns one q-row (q = lane&15) and 16 k-values -> in-lane softmax, per-lane
// contiguous float4 pe loads. P^T through wave-private LDS; PV computes O^T
// with A = V^T (direct global), B = P^T. No __syncthreads anywhere.

__global__ __launch_bounds__(256) void k_attn(
    const unsigned short* __restrict__ q, const unsigned short* __restrict__ k,
    const unsigned short* __restrict__ vt, const float* __restrict__ pe,
    unsigned short* __restrict__ att) {
  __shared__ __align__(16) unsigned short P[4][16][72];  // 9 KB, wave-private

  const int h = blockIdx.y, b = blockIdx.z;
  const int xi = (blockIdx.x + (blockIdx.z << 4)) & 31;
  const int qt = (xi < 16) ? xi : 47 - xi;  // same-CU (z-pair) blocks sum to 33 k-tiles

  const int lane = threadIdx.x & 63, wave = threadIdx.x >> 6;
  const int lr = lane & 15, lg = lane >> 4;
  const int qrow0 = qt * 64 + wave * 16;
  const int myq = qrow0 + lr;  // this lane's q-row (for S^T/O^T)

  const unsigned short* qp = q + (size_t)(b * NH_ + h) * SS_ * QK_;
  const unsigned short* kp = k + (size_t)(b * NH_ + h) * SS_ * QK_;
  const unsigned short* vp = vt + (size_t)(b * NH_ + h) * VD_ * SS_;
  const float* pep = pe + (size_t)h * SS_ * SS_ + (size_t)myq * SS_;

  // Q fragments (reused every iteration): Q[myq][c*32 + lg*8 ..]
  bf16x8 qf[4];
#pragma unroll
  for (int c = 0; c < 4; c++)
    qf[c] = *reinterpret_cast<const bf16x8*>(qp + (size_t)myq * QK_ + c * 32 + lg * 8);

  f32x4 o[8] = {};                 // O^T frags: d = sub*16+lg*4+r, q = myq
  float m = -1e30f, l = 0.f;
  const float scale = 0.08838834764831845f;  // 1/sqrt(128)

  for (int kt = 0; kt <= qt; kt++) {
    const int kbase = kt * 64;

    // V^T fragments, issued first (completed in-order before later loads' waits)
    bf16x8 vf[2][8];
#pragma unroll
    for (int kk = 0; kk < 2; kk++)
#pragma unroll
      for (int sub = 0; sub < 8; sub++)
        vf[kk][sub] = *reinterpret_cast<const bf16x8*>(
            vp + (size_t)(sub * 16 + lr) * SS_ + kbase + kk * 32 + lg * 8);

    // pe: 4 contiguous float4 per lane (k fast axis)
    f32x4 pe4[4];
#pragma unroll
    for (int ck = 0; ck < 4; ck++)
      pe4[ck] = *reinterpret_cast<const f32x4*>(pep + kbase + ck * 16 + lg * 4);

    // S^T = K * Q^T : sc[ck][r] = S[myq][kbase + ck*16 + lg*4 + r]
    f32x4 sc[4];
#pragma unroll
    for (int ck = 0; ck < 4; ck++) {
      f32x4 a = {};
#pragma unroll
      for (int c = 0; c < 4; c++) {
        const bf16x8 kf = *reinterpret_cast<const bf16x8*>(
            kp + (size_t)(kbase + ck * 16 + lr) * QK_ + c * 32 + lg * 8);
        a = mfma16(kf, qf[c], a);
      }
      sc[ck] = a;
    }

    // scale + pe + causal (diag tile only), in-lane max
    const bool diag = (kt == qt);
    float tm = -1e30f;
#pragma unroll
    for (int ck = 0; ck < 4; ck++) {
#pragma unroll
      for (int r = 0; r < 4; r++) {
        float v = fmaf(sc[ck][r], scale, pe4[ck][r]);
        if (diag && (kbase + ck * 16 + lg * 4 + r) > myq) v = -1e30f;
        sc[ck][r] = v;
        tm = fmaxf(tm, v);
      }
    }
    // cross-lg reduce (lanes lr, lr+16, lr+32, lr+48 hold same q)
    tm = fmaxf(tm, __shfl_xor(tm, 16));
    tm = fmaxf(tm, __shfl_xor(tm, 32));

    const float mnew = fmaxf(m, tm);
    const float ps = __expf(m - mnew);
    m = mnew;
    float rsum = 0.f;
#pragma unroll
    for (int ck = 0; ck < 4; ck++)
#pragma unroll
      for (int r = 0; r < 4; r++) {
        const float p = __expf(sc[ck][r] - mnew);
        sc[ck][r] = p;
        rsum += p;
      }
    rsum += __shfl_xor(rsum, 16);
    rsum += __shfl_xor(rsum, 32);
    l = l * ps + rsum;
#pragma unroll
    for (int sub = 0; sub < 8; sub++)
#pragma unroll
      for (int r = 0; r < 4; r++) o[sub][r] *= ps;

    // P^T -> wave-private LDS: P[wave][q=lr][k], 8B packed per ck
#pragma unroll
    for (int ck = 0; ck < 4; ck++) {
      ushort4v pk;
#pragma unroll
      for (int r = 0; r < 4; r++) pk[r] = f2bf(sc[ck][r]);
      *reinterpret_cast<ushort4v*>(&P[wave][lr][ck * 16 + lg * 4]) = pk;
    }

    // PV: O^T[d][q] += V^T-frag * P^T-frag
#pragma unroll
    for (int kk = 0; kk < 2; kk++) {
      const bf16x8 pf = *reinterpret_cast<const bf16x8*>(&P[wave][lr][kk * 32 + lg * 8]);
#pragma unroll
      for (int sub = 0; sub < 8; sub++)
        o[sub] = mfma16(vf[kk][sub], pf, o[sub]);
    }
  }

  // epilogue: lane's q = myq; d = sub*16 + lg*4 + r (4 consecutive -> 8B stores)
  const float inv = 1.0f / l;
  unsigned short* ob = att + (size_t)(b * SS_ + myq) * (NH_ * VD_) + h * VD_;
#pragma unroll
  for (int sub = 0; sub < 8; sub++) {
    ushort4v pk;
#pragma unroll
    for (int r = 0; r < 4; r++) pk[r] = f2bf(o[sub][r] * inv);
    *reinterpret_cast<ushort4v*>(ob + sub * 16 + lg * 4) = pk;
  }
}

// ---------------- launcher ----------------

extern "C" void kernel_launch(void* const* d_in, const int* in_sizes, int n_in,
                              void* d_out, int out_size, void* d_ws, size_t ws_size,
                              hipStream_t stream) {
  const float* x    = (const float*)d_in[0];
  const float* pe   = (const float*)d_in[3];
  const float* wq_w = (const float*)d_in[4];
  const float* wq_b = (const float*)d_in[5];
  const float* wk_w = (const float*)d_in[6];
  const float* wk_b = (const float*)d_in[7];
  const float* wv_w = (const float*)d_in[8];
  const float* wv_b = (const float*)d_in[9];
  const float* wo_w = (const float*)d_in[10];
  const float* wo_b = (const float*)d_in[11];
  float* out = (float*)d_out;

  char* ws = (char*)d_ws;
  unsigned short* x_bf   = (unsigned short*)(ws);                 // 4 MB
  unsigned short* wqkv_t = (unsigned short*)(ws + 4194304);       // 3 MB
  unsigned short* wo_t   = (unsigned short*)(ws + 7340032);       // 1 MB
  float*          qkv_b  = (float*)(ws + 8388608);                // 12 KB
  unsigned short* qb     = (unsigned short*)(ws + 8400896);       // 8 MB
  unsigned short* kb     = (unsigned short*)(ws + 16789504);      // 8 MB
  unsigned short* vtb    = (unsigned short*)(ws + 25178112);      // 8 MB
  unsigned short* attb   = (unsigned short*)(ws + 33566720);      // 8 MB

  k_convert_x<<<2048, 256, 0, stream>>>(x, x_bf, (4096 * 512) / 4);
  {
    dim3 gt(16, 8);  // C=1024, R=512
    k_transpose_cvt<<<gt, 256, 0, stream>>>(wq_w, wqkv_t, 512, 1024);
    k_transpose_cvt<<<gt, 256, 0, stream>>>(wk_w, wqkv_t + 1024 * 512, 512, 1024);
    k_transpose_cvt<<<gt, 256, 0, stream>>>(wv_w, wqkv_t + 2048 * 512, 512, 1024);
    dim3 gt2(8, 16);  // C=512, R=1024
    k_transpose_cvt<<<gt2, 256, 0, stream>>>(wo_w, wo_t, 1024, 512);
  }
  k_concat_bias<<<12, 256, 0, stream>>>(wq_b, wk_b, wv_b, qkv_b);

  dim3 g1(24, 32);
  k_gemm_bt<0><<<g1, 256, 0, stream>>>(x_bf, wqkv_t, qkv_b, 512, qb, kb, vtb, nullptr);

  dim3 g2(32, NH_, BB_);
  k_attn<<<g2, 256, 0, stream>>>(qb, kb, vtb, pe, attb);

  dim3 g3(4, 32);
  k_gemm_bt<1><<<g3, 256, 0, stream>>>(attb, wo_t, wo_b, 1024, nullptr, nullptr, nullptr, out);
}